// Round 16
// baseline (1686.338 us; speedup 1.0000x reference)
//
#include <hip/hip_runtime.h>
#include <hip/hip_bf16.h>
#include <cstdint>
#include <cstddef>

#define DEVI __device__ __forceinline__

#define BB 2
#define S_LEN 2048
#define HID_DIM 4096
#define NH 128
#define PD 64
#define NS 128
#define NG 8
#define INTER 8192
#define CONVD 10240
#define PROJ 18560
#define PROJP 18688
#define NC 16
#define BS 4096
#define GN 1024

using short8 = __attribute__((ext_vector_type(8))) short;
using short4v = __attribute__((ext_vector_type(4))) short;
using f32x4  = __attribute__((ext_vector_type(4))) float;
using bf16x8 = __attribute__((ext_vector_type(8))) __bf16;

DEVI float bf2f(short u) {
  union { unsigned int i; float f; } v;
  v.i = ((unsigned int)(unsigned short)u) << 16;
  return v.f;
}
DEVI short f2bf(float f) {
  union { float ff; unsigned int i; } v; v.ff = f;
  unsigned int x = v.i;
  return (short)((x + 0x7fffu + ((x >> 16) & 1u)) >> 16);
}
DEVI f32x4 mfma16(short8 a, short8 b, f32x4 c) {
  return __builtin_amdgcn_mfma_f32_16x16x32_bf16(
      __builtin_bit_cast(bf16x8, a), __builtin_bit_cast(bf16x8, b), c, 0, 0, 0);
}
DEVI void gl_lds16(const short* g, short* l) {
  __builtin_amdgcn_global_load_lds(
      (const __attribute__((address_space(1))) void*)g,
      (__attribute__((address_space(3))) void*)l, 16, 0, 0);
}
DEVI float sigmoidf_(float x) { return 1.f / (1.f + __expf(-x)); }

__global__ __launch_bounds__(256) void cvt_f32_bf16_k(const float* __restrict__ in,
                                                      short* __restrict__ out, size_t n) {
  size_t i = ((size_t)blockIdx.x * 256 + threadIdx.x) * 8;
  if (i + 8 > n) return;
  float4 a = *(const float4*)(in + i);
  float4 b = *(const float4*)(in + i + 4);
  short8 o;
  o[0] = f2bf(a.x); o[1] = f2bf(a.y); o[2] = f2bf(a.z); o[3] = f2bf(a.w);
  o[4] = f2bf(b.x); o[5] = f2bf(b.y); o[6] = f2bf(b.z); o[7] = f2bf(b.w);
  *(short8*)(out + i) = o;
}

// ---- 256x256 GEMM, merged-iter, B from fp32 (ledger in round notes) ----
#define STGA(BUF, KH, TILE) do { \
  short* _lb = lds_ + ((BUF)*2+(KH))*8192; \
  const int _kt = (TILE)*64 + (KH)*32; \
  { int _row = (wid*2)*16 + srow; int _sl = sps ^ ((_row>>1)&3); \
    gl_lds16(A + (size_t)(m0+_row)*K + _kt + _sl*8, _lb + (wid*2)*512); } \
  { int _row = (wid*2+1)*16 + srow; int _sl = sps ^ ((_row>>1)&3); \
    gl_lds16(A + (size_t)(m0+_row)*K + _kt + _sl*8, _lb + (wid*2+1)*512); } \
} while(0)

#define VM8 asm volatile("s_waitcnt vmcnt(8)" ::: "memory")
#define VM4 asm volatile("s_waitcnt vmcnt(4)" ::: "memory")
#define VM0 asm volatile("s_waitcnt vmcnt(0)" ::: "memory")

#define LDBGF(TILE) do { \
  int _brow = n0 + wid*32 + (lane>>1); if (_brow >= Nrows) _brow = Nrows - 1; \
  const float* _bp = Btf + (size_t)_brow * K + (TILE)*64 + (lane&1)*16; \
  b8[0] = *(const float4*)(_bp);      b8[1] = *(const float4*)(_bp + 4); \
  b8[2] = *(const float4*)(_bp + 8);  b8[3] = *(const float4*)(_bp + 12); \
  b8[4] = *(const float4*)(_bp + 32); b8[5] = *(const float4*)(_bp + 36); \
  b8[6] = *(const float4*)(_bp + 40); b8[7] = *(const float4*)(_bp + 44); \
} while(0)

#define CVWRB(BUF) do { \
  const int _row = wid*32 + (lane>>1); \
  const int _sw = (_row>>1)&3; \
  const int _sgb = (lane&1)*2; \
  _Pragma("unroll") \
  for (int _h = 0; _h < 2; ++_h) \
    _Pragma("unroll") \
    for (int _s = 0; _s < 2; ++_s) { \
      float4 _x = b8[_h*4 + _s*2], _y = b8[_h*4 + _s*2 + 1]; \
      short8 _o; \
      _o[0]=f2bf(_x.x); _o[1]=f2bf(_x.y); _o[2]=f2bf(_x.z); _o[3]=f2bf(_x.w); \
      _o[4]=f2bf(_y.x); _o[5]=f2bf(_y.y); _o[6]=f2bf(_y.z); _o[7]=f2bf(_y.w); \
      *(short8*)(lds_ + 32768 + ((BUF)*2+_h)*8192 + _row*32 + (((_sgb+_s) ^ _sw)<<3)) = _o; \
    } \
} while(0)

#define LDAF(DST, BUF, KH, MIH) do { \
  _Pragma("unroll") \
  for (int _m = 0; _m < 4; ++_m) { \
    int _row = wr*128 + ((MIH)*4+_m)*16 + fr; \
    DST[_m] = *(const short8*)(lds_ + ((BUF)*2+(KH))*8192 + _row*32 + ((slot ^ ((_row>>1)&3))<<3)); \
  } \
} while(0)

#define LDBF(DST, BUF, KH) do { \
  _Pragma("unroll") \
  for (int _n = 0; _n < 4; ++_n) { \
    int _row = wc*64 + _n*16 + fr; \
    DST[_n] = *(const short8*)(lds_ + 32768 + ((BUF)*2+(KH))*8192 + _row*32 + ((slot ^ ((_row>>1)&3))<<3)); \
  } \
} while(0)

#define MFMA16X(MIH, AF, BF) do { \
  _Pragma("unroll") \
  for (int _m = 0; _m < 4; ++_m) \
    _Pragma("unroll") \
    for (int _n = 0; _n < 4; ++_n) \
      acc[(MIH)*4+_m][_n] = mfma16(AF[_m], BF[_n], acc[(MIH)*4+_m][_n]); \
} while(0)

#define ITERF(CB, NB, TNEXT, DOSTG, VMBAR) do { \
  if (DOSTG) LDBGF(TNEXT); \
  VMBAR; \
  __builtin_amdgcn_s_barrier(); \
  LDAF(af0, CB, 0, 0); LDAF(af1, CB, 1, 0); \
  LDBF(bf0, CB, 0); LDBF(bf1, CB, 1); \
  if (DOSTG) STGA(NB, 0, TNEXT); \
  __builtin_amdgcn_s_setprio(1); \
  MFMA16X(0, af0, bf0); \
  MFMA16X(0, af1, bf1); \
  __builtin_amdgcn_s_setprio(0); \
  if (DOSTG) STGA(NB, 1, TNEXT); \
  LDAF(af0, CB, 0, 1); LDAF(af1, CB, 1, 1); \
  __builtin_amdgcn_s_setprio(1); \
  MFMA16X(1, af0, bf0); \
  MFMA16X(1, af1, bf1); \
  __builtin_amdgcn_s_setprio(0); \
  if (DOSTG) { VM4; CVWRB(NB); } \
  asm volatile("s_waitcnt lgkmcnt(0)" ::: "memory"); \
  __builtin_amdgcn_s_barrier(); \
} while(0)

template<int CB16>
__global__ __launch_bounds__(512, 2) void gemm256_k(const short* __restrict__ A,
                                                    const float* __restrict__ Btf,
                                                    void* __restrict__ Cout,
                                                    int Nstride, int K, int ntn, int Nrows) {
  __shared__ short lds_[65536];
  const int tid = threadIdx.x, wid = tid >> 6, lane = tid & 63;
  const int nwg = gridDim.x, orig = blockIdx.x;
  const int swz = (orig & 7) * (nwg >> 3) + (orig >> 3);
  const int per_group = ntn << 3;
  const int group = swz / per_group;
  const int rem = swz - group * per_group;
  const int m0 = (group * 8 + (rem & 7)) * 256;
  const int n0 = (rem >> 3) * 256;
  const int wr = wid >> 2, wc = wid & 3;
  const int fr = lane & 15, slot = lane >> 4;
  const int srow = lane >> 2, sps = lane & 3;

  f32x4 acc[8][4] = {};
  short8 af0[4], af1[4], bf0[4], bf1[4];
  float4 b8[8];
  const int NT = K >> 6;

  LDBGF(0);
  STGA(0, 0, 0); STGA(0, 1, 0);
  VM4;
  CVWRB(0);
  asm volatile("s_waitcnt lgkmcnt(0)" ::: "memory");

  for (int ii = 0; ii < (NT >> 1) - 1; ++ii) {
    const int t = 2 * ii;
    ITERF(0, 1, t + 1, 1, VM8);
    ITERF(1, 0, t + 2, 1, VM8);
  }
  ITERF(0, 1, NT - 1, 1, VM8);
  ITERF(1, 0, 0, 0, VM0);

  const int er = (lane >> 4) * 4, ec = lane & 15;
  if (CB16) {
    short* C = (short*)Cout;
#pragma unroll
    for (int mi = 0; mi < 8; ++mi)
#pragma unroll
      for (int j = 0; j < 4; ++j) {
        size_t base = (size_t)(m0 + wr * 128 + mi * 16 + er + j) * Nstride + n0 + wc * 64 + ec;
#pragma unroll
        for (int ni = 0; ni < 4; ++ni) C[base + ni * 16] = f2bf(acc[mi][ni][j]);
      }
  } else {
    float* C = (float*)Cout;
#pragma unroll
    for (int mi = 0; mi < 8; ++mi)
#pragma unroll
      for (int j = 0; j < 4; ++j) {
        size_t base = (size_t)(m0 + wr * 128 + mi * 16 + er + j) * Nstride + n0 + wc * 64 + ec;
#pragma unroll
        for (int ni = 0; ni < 4; ++ni) C[base + ni * 16] = acc[mi][ni][j];
      }
  }
}

__global__ __launch_bounds__(256) void conv_silu_k(const short* __restrict__ projb,
                                                   const float* __restrict__ convw,
                                                   const float* __restrict__ convb,
                                                   short* __restrict__ hbc) {
  const int c = blockIdx.x * 256 + threadIdx.x;
  const int s0 = blockIdx.y * 256;
  const int b = blockIdx.z;
  const size_t rb = (size_t)b * S_LEN;
  const float* wp = convw + (size_t)c * 4;
  const float w0 = wp[0], w1 = wp[1], w2 = wp[2], w3 = wp[3];
  const float bias = convb[c];
  const short* pcol = projb + INTER + c;
  float x1 = 0.f, x2 = 0.f, x3 = 0.f;
  if (s0 > 0) {
    x3 = bf2f(pcol[(rb + s0 - 3) * PROJP]);
    x2 = bf2f(pcol[(rb + s0 - 2) * PROJP]);
    x1 = bf2f(pcol[(rb + s0 - 1) * PROJP]);
  }
  for (int s = s0; s < s0 + 256; ++s) {
    float v = bf2f(pcol[(rb + s) * PROJP]);
    float acc = bias + w0 * x3 + w1 * x2 + w2 * x1 + w3 * v;
    float o = acc * sigmoidf_(acc);
    hbc[(rb + s) * CONVD + c] = f2bf(o);
    x3 = x2; x2 = x1; x1 = v;
  }
}

__global__ __launch_bounds__(128) void acum_k(const short* __restrict__ projb,
                                              const float* __restrict__ dt_bias,
                                              const float* __restrict__ A_log,
                                              float* __restrict__ dtT,
                                              float* __restrict__ acum) {
  const int l = threadIdx.x;
  const int lane = l & 63, wv = l >> 6;
  const int z = blockIdx.x, h = blockIdx.y, b = blockIdx.z;
  const float A = -__expf(A_log[h]);
  __shared__ float w0tot;
  const int r = b * S_LEN + z * 128 + l;
  float xv = bf2f(projb[(size_t)r * PROJP + INTER + CONVD + h]) + dt_bias[h];
  float sp = (xv > 20.f) ? xv : log1pf(__expf(xv));
  sp = fminf(fmaxf(sp, 0.f), 100.f);
  const size_t base = ((size_t)(b * NH + h)) * S_LEN + z * 128;
  dtT[base + l] = sp;
  float val = sp * A;
#pragma unroll
  for (int off = 1; off < 64; off <<= 1) {
    float t = __shfl_up(val, off, 64);
    if (lane >= off) val += t;
  }
  if (wv == 0 && lane == 63) w0tot = val;
  __syncthreads();
  if (wv == 1) val += w0tot;
  acum[base + l] = val;
}

__global__ __launch_bounds__(512) void states_k(const short* __restrict__ hbc,
                                                const float* __restrict__ dtT,
                                                const float* __restrict__ acum,
                                                float* __restrict__ states) {
  __shared__ short sBT[128 * 136];
  __shared__ short sxdt2[2][64 * 136];
  const int tid = threadIdx.x, wid = tid >> 6, lane = tid & 63;
  const int g = blockIdx.x, z = blockIdx.y, b = blockIdx.z;
  const size_t srow0 = (size_t)(b * S_LEN + z * 128);
  const short* hrow = hbc + srow0 * CONVD;

  {
    const int l = tid & 127, n0b = (tid >> 7) * 32;
    const short* src = hrow + (size_t)l * CONVD + INTER + g * NS + n0b;
    short8 v0 = *(const short8*)(src);
    short8 v1 = *(const short8*)(src + 8);
    short8 v2 = *(const short8*)(src + 16);
    short8 v3 = *(const short8*)(src + 24);
#pragma unroll
    for (int j = 0; j < 8; ++j) {
      sBT[(n0b + j) * 136 + l] = v0[j];
      sBT[(n0b + 8 + j) * 136 + l] = v1[j];
      sBT[(n0b + 16 + j) * 136 + l] = v2[j];
      sBT[(n0b + 24 + j) * 136 + l] = v3[j];
    }
  }

  const int fr = lane & 15, fk8 = (lane >> 4) * 8;
  const int er = (lane >> 4) * 4, ec = lane & 15;
  const int pband = (wid & 3) * 16, nhalf = (wid >> 2) * 64;
  const int s2 = tid & 63, p0w = (tid >> 6) * 8;

  float cdv0, cdv1; short8 cr0, cr1;
  {
    const int h = g * 16;
    const float* acg = acum + ((size_t)(b * NH + h)) * S_LEN + z * 128;
    const float* dts = dtT + ((size_t)(b * NH + h)) * S_LEN + z * 128;
    const float acL = acg[127];
    cdv0 = dts[2 * s2] * __expf(acL - acg[2 * s2]);
    cdv1 = dts[2 * s2 + 1] * __expf(acL - acg[2 * s2 + 1]);
    const short* rsrc = hrow + (size_t)(2 * s2) * CONVD + (size_t)h * PD + p0w;
    cr0 = *(const short8*)(rsrc);
    cr1 = *(const short8*)(rsrc + CONVD);
  }
  {
    unsigned int* x32 = (unsigned int*)sxdt2[0];
#pragma unroll
    for (int j = 0; j < 8; ++j) {
      unsigned int lo = (unsigned short)f2bf(bf2f(cr0[j]) * cdv0);
      unsigned int hi = (unsigned short)f2bf(bf2f(cr1[j]) * cdv1);
      x32[(p0w + j) * 68 + s2] = lo | (hi << 16);
    }
  }
  __syncthreads();

  for (int hh = 0; hh < 16; ++hh) {
    const int h = g * 16 + hh;
    float ndv0 = 0.f, ndv1 = 0.f; short8 nr0, nr1;
    if (hh < 15) {
      const int h2 = h + 1;
      const float* acg = acum + ((size_t)(b * NH + h2)) * S_LEN + z * 128;
      const float* dts = dtT + ((size_t)(b * NH + h2)) * S_LEN + z * 128;
      const float acL = acg[127];
      ndv0 = dts[2 * s2] * __expf(acL - acg[2 * s2]);
      ndv1 = dts[2 * s2 + 1] * __expf(acL - acg[2 * s2 + 1]);
      const short* rsrc = hrow + (size_t)(2 * s2) * CONVD + (size_t)h2 * PD + p0w;
      nr0 = *(const short8*)(rsrc);
      nr1 = *(const short8*)(rsrc + CONVD);
    }
    const short* sx = sxdt2[hh & 1];
    f32x4 st[4] = {};
#pragma unroll
    for (int kk = 0; kk < 4; ++kk) {
      short8 a = *(const short8*)(sx + (pband + fr) * 136 + kk * 32 + fk8);
#pragma unroll
      for (int ni = 0; ni < 4; ++ni) {
        short8 bb = *(const short8*)(sBT + (nhalf + ni * 16 + fr) * 136 + kk * 32 + fk8);
        st[ni] = mfma16(a, bb, st[ni]);
      }
    }
    float* stp = states + (((size_t)(b * NC + z)) * NH + h) * (size_t)(NS * PD);
#pragma unroll
    for (int ni = 0; ni < 4; ++ni)
#pragma unroll
      for (int j = 0; j < 4; ++j)
        stp[(pband + er + j) * NS + nhalf + ni * 16 + ec] = st[ni][j];
    if (hh < 15) {
      unsigned int* x32 = (unsigned int*)sxdt2[(hh + 1) & 1];
#pragma unroll
      for (int j = 0; j < 8; ++j) {
        unsigned int lo = (unsigned short)f2bf(bf2f(nr0[j]) * ndv0);
        unsigned int hi = (unsigned short)f2bf(bf2f(nr1[j]) * ndv1);
        x32[(p0w + j) * 68 + s2] = lo | (hi << 16);
      }
    }
    __syncthreads();
  }
}

__global__ __launch_bounds__(256) void scan_k(float* __restrict__ states,
                                              const float* __restrict__ acum) {
  const int h = blockIdx.x, b = blockIdx.y;
  const int tid = threadIdx.x;
  float* stp = states + ((size_t)(b * NC * NH) + h) * (size_t)(NS * PD);
  const size_t cst = (size_t)NH * NS * PD;
  const float* ac = acum + ((size_t)(b * NH + h)) * S_LEN;
  float E[32];
#pragma unroll
  for (int i = 0; i < 32; ++i) E[i] = 0.f;
  const int n = tid & 127, pg = tid >> 7;
  for (int zz = 0; zz < NC; ++zz) {
    float* sz = stp + (size_t)zz * cst;
    short* pvb = (short*)sz;
    float tmp[32];
#pragma unroll
    for (int i = 0; i < 32; ++i) tmp[i] = sz[i * 256 + tid];
    __syncthreads();
    float dec = __expf(ac[zz * 128 + 127]);
#pragma unroll
    for (int i = 0; i < 32; ++i) {
      int p = i * 2 + pg;
      pvb[p * 128 + n] = f2bf(E[i]);
      E[i] = dec * E[i] + tmp[i];
    }
    __syncthreads();
  }
}

#define RDSW(BUF, ROWBASE, KK) \
  (*(const short8*)((BUF) + ((ROWBASE) + fr) * 128 + ((((KK) * 4 + slot4) ^ sw7) << 3)))

#define WRX(DST, D0, D1, R0, R1) do { \
  unsigned int* _x = (unsigned int*)(DST); \
  _Pragma("unroll") \
  for (int _j = 0; _j < 8; ++_j) { \
    unsigned int _lo = (unsigned short)f2bf(bf2f(R0[_j]) * (D0)); \
    unsigned int _hi = (unsigned short)f2bf(bf2f(R1[_j]) * (D1)); \
    _x[(p0w + _j) * 64 + ((((s2 >> 2) ^ _j) << 2) | (s2 & 3))] = _lo | (_hi << 16); \
  } \
} while (0)

#define WRP(DST, P0, P1) do { \
  int _p = tid >> 3; int _s0 = (tid & 7) * 2; int _m = _p & 7; \
  *(short8*)((DST) + _p * 128 + ((_s0 ^ _m) << 3)) = P0; \
  *(short8*)((DST) + _p * 128 + (((_s0 + 1) ^ _m) << 3)) = P1; \
} while (0)

#define LOADH_Y(H, DT0, DT1, ACS, ACL, R0, R1, P0, P1) do { \
  const float* _ac = acum + ((size_t)(b * NH + (H))) * S_LEN + z * 128; \
  const float* _dts = dtT + ((size_t)(b * NH + (H))) * S_LEN + z * 128; \
  DT0 = _dts[2 * s2]; DT1 = _dts[2 * s2 + 1]; \
  _Pragma("unroll") \
  for (int _si = 0; _si < 8; ++_si) ACS[_si] = _ac[_si * 16 + ec]; \
  _Pragma("unroll") \
  for (int _j = 0; _j < 4; ++_j) ACL[_j] = _ac[lrow + er + _j]; \
  const short* _rs = hrow + (size_t)(2 * s2) * CONVD + (size_t)(H) * PD + p0w; \
  R0 = *(const short8*)(_rs); R1 = *(const short8*)(_rs + CONVD); \
  const short* _pv = (const short*)(states + (((size_t)(b * NC + z)) * NH + (H)) * (size_t)(NS * PD)); \
  P0 = *(const short8*)(_pv + tid * 16); P1 = *(const short8*)(_pv + tid * 16 + 8); \
} while (0)

__global__ __launch_bounds__(512) void yfull_k(const short* __restrict__ hbc,
                                               const short* __restrict__ projb,
                                               const float* __restrict__ dtT,
                                               const float* __restrict__ acum,
                                               const float* __restrict__ states,
                                               const float* __restrict__ Dv,
                                               const float* __restrict__ norm_w,
                                               short* __restrict__ normed) {
  __shared__ short lds[66560];
  __shared__ float sScale[128];
  __shared__ float sNW[1024];
  short* sC = lds;
  short* sB = lds + 16384;
  short* sx0 = lds + 32768;
  short* sp0 = lds + 40960;
  const int tid = threadIdx.x, wid = tid >> 6, lane = tid & 63;
  short* sPw = lds + 49152 + wid * 2176;
  const int g = blockIdx.x, z = blockIdx.y, b = blockIdx.z;
  const size_t srow0 = (size_t)(b * S_LEN + z * 128);
  const short* hrow = hbc + srow0 * CONVD;

  {
    const int slot_g = (lane & 15) ^ (((wid & 1) << 2) | (lane >> 4));
    const int n0_ = slot_g * 8;
#pragma unroll
    for (int it = 0; it < 4; ++it) {
      int s = it * 32 + wid * 4 + (lane >> 4);
      gl_lds16(hrow + (size_t)s * CONVD + INTER + GN + g * NS + n0_, sC + (it * 32 + wid * 4) * 128);
      gl_lds16(hrow + (size_t)s * CONVD + INTER + g * NS + n0_, sB + (it * 32 + wid * 4) * 128);
    }
  }
  for (int i = tid; i < 1024; i += 512) sNW[i] = norm_w[g * 1024 + i];
  __syncthreads();

  const int fr = lane & 15, fk8 = (lane >> 4) * 8;
  const int slot4 = lane >> 4, sw7 = lane & 7;
  const int er = (lane >> 4) * 4, ec = lane & 15;
  const int lrow = wid * 16;
  const int s2 = tid & 63, p0w = (tid >> 6) * 8;

  float cdt0, cdt1, cacS[8], cacl[4];
  short8 cr0, cr1, cp0, cp1;
  LOADH_Y(g * 16, cdt0, cdt1, cacS, cacl, cr0, cr1, cp0, cp1);

  f32x4 sc[8] = {};
#pragma unroll
  for (int kk = 0; kk < 4; ++kk) {
    short8 a = RDSW(sC, lrow, kk);
#pragma unroll
    for (int si = 0; si < 8; ++si) {
      short8 bv = RDSW(sB, si * 16, kk);
      sc[si] = mfma16(a, bv, sc[si]);
    }
  }
  WRX(sx0, cdt0, cdt1, cr0, cr1);
  WRP(sp0, cp0, cp1);
  __syncthreads();

  float rssq[4] = {0.f, 0.f, 0.f, 0.f};

  for (int hh = 0; hh < 16; ++hh) {
    const int h = g * 16 + hh;
    float ndt0 = 0.f, ndt1 = 0.f, nacS[8], nacl[4];
    short8 nr0, nr1, np0, np1;
    if (hh < 15) LOADH_Y(h + 1, ndt0, ndt1, nacS, nacl, nr0, nr1, np0, np1);

    short* sx = (hh & 1) ? sB : sx0;
    short* sp = (hh & 1) ? (sB + 8192) : sp0;

#pragma unroll
    for (int j = 0; j < 4; ++j) {
      int lloc = er + j;
      float acl = cacl[j];
#pragma unroll
      for (int si = 0; si < 8; ++si) {
        int sI = si * 16 + ec;
        float v = (sI <= lrow + lloc) ? sc[si][j] * __expf(acl - cacS[si]) : 0.f;
        sPw[lloc * 136 + sI] = f2bf(v);
      }
    }
    f32x4 yd[4] = {}, yo[4] = {};
#pragma unroll
    for (int kk = 0; kk < 4; ++kk) {
      short8 ap = *(const short8*)(sPw + fr * 136 + kk * 32 + fk8);
      short8 acf = RDSW(sC, lrow, kk);
#pragma unroll
      for (int ni = 0; ni < 4; ++ni) {
        short8 bv = RDSW(sx, ni * 16, kk);
        yd[ni] = mfma16(ap, bv, yd[ni]);
        short8 bp = RDSW(sp, ni * 16, kk);
        yo[ni] = mfma16(acf, bp, yo[ni]);
      }
    }
    const float Dh = Dv[h];
#pragma unroll
    for (int j = 0; j < 4; ++j) {
      int l = lrow + er + j;
      float e_ac = __expf(cacl[j]);
#pragma unroll
      for (int ni = 0; ni < 4; ++ni) {
        int p = ni * 16 + ec;
        float hs = bf2f(hrow[(size_t)l * CONVD + (size_t)h * PD + p]);
        float y = yd[ni][j] + yo[ni][j] * e_ac + hs * Dh;
        float gate = bf2f(projb[(srow0 + l) * (size_t)PROJP + (size_t)h * PD + p]);
        float gg = y * gate * sigmoidf_(gate);
        normed[(srow0 + l) * (size_t)INTER + (size_t)h * PD + p] = f2bf(gg);
        rssq[j] += gg * gg;
      }
    }
    if (hh < 15) {
      short* nx = (hh & 1) ? sx0 : sB;
      short* npv = (hh & 1) ? sp0 : (sB + 8192);
      WRX(nx, ndt0, ndt1, nr0, nr1);
      WRP(npv, np0, np1);
      cdt0 = ndt0; cdt1 = ndt1; cr0 = nr0; cr1 = nr1; cp0 = np0; cp1 = np1;
#pragma unroll
      for (int si = 0; si < 8; ++si) cacS[si] = nacS[si];
#pragma unroll
      for (int j = 0; j < 4; ++j) cacl[j] = nacl[j];
    }
    __syncthreads();
  }

#pragma unroll
  for (int j = 0; j < 4; ++j) {
#pragma unroll
    for (int m = 1; m <= 8; m <<= 1) rssq[j] += __shfl_xor(rssq[j], m, 64);
  }
  if (ec == 0) {
#pragma unroll
    for (int j = 0; j < 4; ++j) sScale[lrow + er + j] = rsqrtf(rssq[j] * (1.f / 1024.f) + 1e-5f);
  }
  __syncthreads();

  for (int e = tid * 8; e < 128 * 1024; e += 4096) {
    int row = e >> 10, ch = e & 1023;
    short* gp = normed + (srow0 + row) * (size_t)INTER + g * 1024 + ch;
    short8 gv = *(const short8*)(gp);
    float scl = sScale[row];
    short8 o;
#pragma unroll
    for (int q = 0; q < 8; ++q) o[q] = f2bf(bf2f(gv[q]) * scl * sNW[ch + q]);
    *(short8*)(gp) = o;
  }
}

// ----------------------------------------------------------------
extern "C" void kernel_launch(void* const* d_in, const int* in_sizes, int n_in,
                              void* d_out, int out_size, void* d_ws, size_t ws_size,
                              hipStream_t stream) {
  const float* x     = (const float*)d_in[0];
  const float* w1    = (const float*)d_in[1];
  const float* convw = (const float*)d_in[2];
  const float* convb = (const float*)d_in[3];
  const float* dtb   = (const float*)d_in[4];
  const float* alog  = (const float*)d_in[5];
  const float* Dv    = (const float*)d_in[6];
  const float* nw    = (const float*)d_in[7];
  const float* w2    = (const float*)d_in[8];
  float* out = (float*)d_out;

  char* ws = (char*)d_ws;
  size_t off = 0;
  float* dtT = (float*)(ws + off);  off += (size_t)BB * NH * S_LEN * 4;
  float* acum = (float*)(ws + off); off += (size_t)BB * NH * S_LEN * 4;
  short* xb = (short*)(ws + off);   off += (size_t)BS * HID_DIM * 2;
  short* normed = (short*)(ws + off); off += (size_t)BS * INTER * 2;
  short* projb = (short*)(ws + off); off += (size_t)BS * PROJP * 2;
  short* hbc = (short*)(ws + off);   off += (size_t)BS * CONVD * 2;
  float* states = (float*)(ws + off); off += (size_t)BB * NC * NH * NS * PD * 4;

  const size_t nx = (size_t)BS * HID_DIM;

  cvt_f32_bf16_k<<<dim3(nx / 2048), 256, 0, stream>>>(x, xb, nx);

  // gemm1: [4096 x 18560(pad 18688)] = xb * w1(fp32)^T ; B rows clamped to 18559
  gemm256_k<1><<<dim3(16 * 73), 512, 0, stream>>>(xb, w1, projb, PROJP, HID_DIM, 73, PROJ);

  conv_silu_k<<<dim3(CONVD / 256, S_LEN / 256, BB), 256, 0, stream>>>(projb, convw, convb, hbc);
  acum_k<<<dim3(NC, NH, BB), 128, 0, stream>>>(projb, dtb, alog, dtT, acum);

  states_k<<<dim3(NG, NC, BB), 512, 0, stream>>>(hbc, dtT, acum, states);
  scan_k<<<dim3(NH, BB), 256, 0, stream>>>(states, acum);
  yfull_k<<<dim3(NG, NC, BB), 512, 0, stream>>>(hbc, projb, dtT, acum, states, Dv, nw, normed);

  // gemm2: [4096 x 4096] = normed * w2(fp32)^T
  gemm256_k<0><<<dim3(16 * 16), 512, 0, stream>>>(normed, w2, out, HID_DIM, INTER, 16, HID_DIM);
}

// Round 17
// 1170.132 us; speedup vs baseline: 1.4412x; 1.4412x over previous
//
#include <hip/hip_runtime.h>
#include <hip/hip_bf16.h>
#include <cstdint>
#include <cstddef>

#define DEVI __device__ __forceinline__

#define BB 2
#define S_LEN 2048
#define HID_DIM 4096
#define NH 128
#define PD 64
#define NS 128
#define NG 8
#define INTER 8192
#define CONVD 10240
#define PROJ 18560
#define PROJP 18688   // padded to 73*256 for 256-wide GEMM tiles
#define NC 16
#define BS 4096
#define GN 1024   // NG*NS

using short8 = __attribute__((ext_vector_type(8))) short;
using short4v = __attribute__((ext_vector_type(4))) short;
using f32x4  = __attribute__((ext_vector_type(4))) float;
using bf16x8 = __attribute__((ext_vector_type(8))) __bf16;

DEVI float bf2f(short u) {
  union { unsigned int i; float f; } v;
  v.i = ((unsigned int)(unsigned short)u) << 16;
  return v.f;
}
DEVI short f2bf(float f) {
  union { float ff; unsigned int i; } v; v.ff = f;
  unsigned int x = v.i;
  return (short)((x + 0x7fffu + ((x >> 16) & 1u)) >> 16);
}
DEVI f32x4 mfma16(short8 a, short8 b, f32x4 c) {
  return __builtin_amdgcn_mfma_f32_16x16x32_bf16(
      __builtin_bit_cast(bf16x8, a), __builtin_bit_cast(bf16x8, b), c, 0, 0, 0);
}
DEVI void gl_lds16(const short* g, short* l) {
  __builtin_amdgcn_global_load_lds(
      (const __attribute__((address_space(1))) void*)g,
      (__attribute__((address_space(3))) void*)l, 16, 0, 0);
}
DEVI float sigmoidf_(float x) { return 1.f / (1.f + __expf(-x)); }

// ---------------------------------------------------------------- converts
__global__ __launch_bounds__(256) void cvt_f32_bf16_k(const float* __restrict__ in,
                                                      short* __restrict__ out, size_t n) {
  size_t i = ((size_t)blockIdx.x * 256 + threadIdx.x) * 8;
  if (i + 8 > n) return;
  float4 a = *(const float4*)(in + i);
  float4 b = *(const float4*)(in + i + 4);
  short8 o;
  o[0] = f2bf(a.x); o[1] = f2bf(a.y); o[2] = f2bf(a.z); o[3] = f2bf(a.w);
  o[4] = f2bf(b.x); o[5] = f2bf(b.y); o[6] = f2bf(b.z); o[7] = f2bf(b.w);
  *(short8*)(out + i) = o;
}

// ---------------------------------------------------------------- 256x256 GEMM, merged-iter (r10/r15, validated 575us)
// K-tile-granular dbuf: iter computes tile t (buf cb), stages t+1 (buf nb).
// 2 barriers + 1 vmcnt per K-tile. Ledger:
//   STG(nb,kh0); VM4; bar1;  -- VM4 drains prev iter's 8 gl_lds (12 outstanding -> 4)
//   read cb MIH0 (A kh0+kh1, B kh0+kh1); 32 MFMA;
//   STG(nb,kh1);             -- writes nb only; reads are cb; no hazard
//   read cb MIH1 (A); 32 MFMA (B frags reused);
//   lgkm0; bar2;             -- cb reads retired before next iter's STG overwrites cb
// Final iter: VM0 at bar1, no staging.

#define STG(ISB, BUF, KH, TILE) do { \
  const short* _src = (ISB) ? Bt : A; \
  const int _r0 = (ISB) ? n0 : m0; \
  short* _lb = lds_ + ((ISB) ? 32768 : 0) + ((BUF)*2+(KH))*8192; \
  const int _kt = (TILE)*64 + (KH)*32; \
  { int _row = (wid*2)*16 + srow; int _sl = sps ^ ((_row>>1)&3); \
    gl_lds16(_src + (size_t)(_r0+_row)*K + _kt + _sl*8, _lb + (wid*2)*512); } \
  { int _row = (wid*2+1)*16 + srow; int _sl = sps ^ ((_row>>1)&3); \
    gl_lds16(_src + (size_t)(_r0+_row)*K + _kt + _sl*8, _lb + (wid*2+1)*512); } \
} while(0)

#define VM4 asm volatile("s_waitcnt vmcnt(4)" ::: "memory")
#define VM0 asm volatile("s_waitcnt vmcnt(0)" ::: "memory")

#define LDAF(DST, BUF, KH, MIH) do { \
  _Pragma("unroll") \
  for (int _m = 0; _m < 4; ++_m) { \
    int _row = wr*128 + ((MIH)*4+_m)*16 + fr; \
    DST[_m] = *(const short8*)(lds_ + ((BUF)*2+(KH))*8192 + _row*32 + ((slot ^ ((_row>>1)&3))<<3)); \
  } \
} while(0)

#define LDBF(DST, BUF, KH) do { \
  _Pragma("unroll") \
  for (int _n = 0; _n < 4; ++_n) { \
    int _row = wc*64 + _n*16 + fr; \
    DST[_n] = *(const short8*)(lds_ + 32768 + ((BUF)*2+(KH))*8192 + _row*32 + ((slot ^ ((_row>>1)&3))<<3)); \
  } \
} while(0)

#define MFMA16X(MIH, AF, BF) do { \
  _Pragma("unroll") \
  for (int _m = 0; _m < 4; ++_m) \
    _Pragma("unroll") \
    for (int _n = 0; _n < 4; ++_n) \
      acc[(MIH)*4+_m][_n] = mfma16(AF[_m], BF[_n], acc[(MIH)*4+_m][_n]); \
} while(0)

#define ITER(CB, NB, TNEXT, DOSTG, VMW) do { \
  if (DOSTG) { STG(0, NB, 0, TNEXT); STG(1, NB, 0, TNEXT); } \
  VMW; \
  __builtin_amdgcn_s_barrier(); \
  LDAF(af0, CB, 0, 0); LDAF(af1, CB, 1, 0); \
  LDBF(bf0, CB, 0); LDBF(bf1, CB, 1); \
  __builtin_amdgcn_s_setprio(1); \
  MFMA16X(0, af0, bf0); \
  MFMA16X(0, af1, bf1); \
  __builtin_amdgcn_s_setprio(0); \
  if (DOSTG) { STG(0, NB, 1, TNEXT); STG(1, NB, 1, TNEXT); } \
  LDAF(af0, CB, 0, 1); LDAF(af1, CB, 1, 1); \
  __builtin_amdgcn_s_setprio(1); \
  MFMA16X(1, af0, bf0); \
  MFMA16X(1, af1, bf1); \
  __builtin_amdgcn_s_setprio(0); \
  asm volatile("s_waitcnt lgkmcnt(0)" ::: "memory"); \
  __builtin_amdgcn_s_barrier(); \
} while(0)

template<int CB16>
__global__ __launch_bounds__(512, 2) void gemm256_k(const short* __restrict__ A,
                                                    const short* __restrict__ Bt,
                                                    void* __restrict__ Cout,
                                                    int Nstride, int K, int ntn) {
  __shared__ short lds_[65536];  // 128 KiB
  const int tid = threadIdx.x, wid = tid >> 6, lane = tid & 63;
  // XCD-bijective chunk + GM=8 m-supertile decode
  const int nwg = gridDim.x, orig = blockIdx.x;
  const int swz = (orig & 7) * (nwg >> 3) + (orig >> 3);
  const int per_group = ntn << 3;
  const int group = swz / per_group;
  const int rem = swz - group * per_group;
  const int m0 = (group * 8 + (rem & 7)) * 256;
  const int n0 = (rem >> 3) * 256;
  const int wr = wid >> 2, wc = wid & 3;
  const int fr = lane & 15, slot = lane >> 4;
  const int srow = lane >> 2, sps = lane & 3;

  f32x4 acc[8][4] = {};
  short8 af0[4], af1[4], bf0[4], bf1[4];
  const int NT = K >> 6;  // even for K=4096/8192

  // prologue: stage tile 0 into buf0 (8 gl_lds ops)
  STG(0, 0, 0, 0); STG(1, 0, 0, 0); STG(0, 0, 1, 0); STG(1, 0, 1, 0);

  for (int ii = 0; ii < (NT >> 1) - 1; ++ii) {
    const int t = 2 * ii;
    ITER(0, 1, t + 1, 1, VM4);
    ITER(1, 0, t + 2, 1, VM4);
  }
  ITER(0, 1, NT - 1, 1, VM4);
  ITER(1, 0, 0, 0, VM0);

  const int er = (lane >> 4) * 4, ec = lane & 15;
  if (CB16) {
    short* C = (short*)Cout;
#pragma unroll
    for (int mi = 0; mi < 8; ++mi)
#pragma unroll
      for (int j = 0; j < 4; ++j) {
        size_t base = (size_t)(m0 + wr * 128 + mi * 16 + er + j) * Nstride + n0 + wc * 64 + ec;
#pragma unroll
        for (int ni = 0; ni < 4; ++ni) C[base + ni * 16] = f2bf(acc[mi][ni][j]);
      }
  } else {
    float* C = (float*)Cout;
#pragma unroll
    for (int mi = 0; mi < 8; ++mi)
#pragma unroll
      for (int j = 0; j < 4; ++j) {
        size_t base = (size_t)(m0 + wr * 128 + mi * 16 + er + j) * Nstride + n0 + wc * 64 + ec;
#pragma unroll
        for (int ni = 0; ni < 4; ++ni) C[base + ni * 16] = acc[mi][ni][j];
      }
  }
}

// ---------------------------------------------------------------- conv + silu (sliding window, read-once)
__global__ __launch_bounds__(256) void conv_silu_k(const short* __restrict__ projb,
                                                   const float* __restrict__ convw,
                                                   const float* __restrict__ convb,
                                                   short* __restrict__ hbc) {
  const int c = blockIdx.x * 256 + threadIdx.x;
  const int s0 = blockIdx.y * 256;
  const int b = blockIdx.z;
  const size_t rb = (size_t)b * S_LEN;
  const float* wp = convw + (size_t)c * 4;
  const float w0 = wp[0], w1 = wp[1], w2 = wp[2], w3 = wp[3];
  const float bias = convb[c];
  const short* pcol = projb + INTER + c;
  float x1 = 0.f, x2 = 0.f, x3 = 0.f;
  if (s0 > 0) {
    x3 = bf2f(pcol[(rb + s0 - 3) * PROJP]);
    x2 = bf2f(pcol[(rb + s0 - 2) * PROJP]);
    x1 = bf2f(pcol[(rb + s0 - 1) * PROJP]);
  }
  for (int s = s0; s < s0 + 256; ++s) {
    float v = bf2f(pcol[(rb + s) * PROJP]);
    float acc = bias + w0 * x3 + w1 * x2 + w2 * x1 + w3 * v;
    float o = acc * sigmoidf_(acc);
    hbc[(rb + s) * CONVD + c] = f2bf(o);
    x3 = x2; x2 = x1; x1 = v;
  }
}

// ---------------------------------------------------------------- dt softplus + per-chunk cumsum (shuffle Kogge-Stone)
__global__ __launch_bounds__(128) void acum_k(const short* __restrict__ projb,
                                              const float* __restrict__ dt_bias,
                                              const float* __restrict__ A_log,
                                              float* __restrict__ dtT,
                                              float* __restrict__ acum) {
  const int l = threadIdx.x;
  const int lane = l & 63, wv = l >> 6;
  const int z = blockIdx.x, h = blockIdx.y, b = blockIdx.z;
  const float A = -__expf(A_log[h]);
  __shared__ float w0tot;
  const int r = b * S_LEN + z * 128 + l;
  float xv = bf2f(projb[(size_t)r * PROJP + INTER + CONVD + h]) + dt_bias[h];
  float sp = (xv > 20.f) ? xv : log1pf(__expf(xv));
  sp = fminf(fmaxf(sp, 0.f), 100.f);
  const size_t base = ((size_t)(b * NH + h)) * S_LEN + z * 128;
  dtT[base + l] = sp;
  float val = sp * A;
#pragma unroll
  for (int off = 1; off < 64; off <<= 1) {
    float t = __shfl_up(val, off, 64);
    if (lane >= off) val += t;
  }
  if (wv == 0 && lane == 63) w0tot = val;
  __syncthreads();
  if (wv == 1) val += w0tot;
  acum[base + l] = val;
}

// ---------------------------------------------------------------- states per (b,z,g)
__global__ __launch_bounds__(512) void states_k(const short* __restrict__ hbc,
                                                const float* __restrict__ dtT,
                                                const float* __restrict__ acum,
                                                float* __restrict__ states) {
  __shared__ short sBT[128 * 136];       // [n][l]
  __shared__ short sxdt2[2][64 * 136];   // [p][s] decayed, double buffer
  const int tid = threadIdx.x, wid = tid >> 6, lane = tid & 63;
  const int g = blockIdx.x, z = blockIdx.y, b = blockIdx.z;
  const size_t srow0 = (size_t)(b * S_LEN + z * 128);
  const short* hrow = hbc + srow0 * CONVD;

  {  // sBT build
    const int l = tid & 127, n0b = (tid >> 7) * 32;
    const short* src = hrow + (size_t)l * CONVD + INTER + g * NS + n0b;
    short8 v0 = *(const short8*)(src);
    short8 v1 = *(const short8*)(src + 8);
    short8 v2 = *(const short8*)(src + 16);
    short8 v3 = *(const short8*)(src + 24);
#pragma unroll
    for (int j = 0; j < 8; ++j) {
      sBT[(n0b + j) * 136 + l] = v0[j];
      sBT[(n0b + 8 + j) * 136 + l] = v1[j];
      sBT[(n0b + 16 + j) * 136 + l] = v2[j];
      sBT[(n0b + 24 + j) * 136 + l] = v3[j];
    }
  }

  const int fr = lane & 15, fk8 = (lane >> 4) * 8;
  const int er = (lane >> 4) * 4, ec = lane & 15;
  const int pband = (wid & 3) * 16, nhalf = (wid >> 2) * 64;
  const int s2 = tid & 63, p0w = (tid >> 6) * 8;

  float cdv0, cdv1; short8 cr0, cr1;
  {  // head 0 load
    const int h = g * 16;
    const float* acg = acum + ((size_t)(b * NH + h)) * S_LEN + z * 128;
    const float* dts = dtT + ((size_t)(b * NH + h)) * S_LEN + z * 128;
    const float acL = acg[127];
    cdv0 = dts[2 * s2] * __expf(acL - acg[2 * s2]);
    cdv1 = dts[2 * s2 + 1] * __expf(acL - acg[2 * s2 + 1]);
    const short* rsrc = hrow + (size_t)(2 * s2) * CONVD + (size_t)h * PD + p0w;
    cr0 = *(const short8*)(rsrc);
    cr1 = *(const short8*)(rsrc + CONVD);
  }
  {
    unsigned int* x32 = (unsigned int*)sxdt2[0];
#pragma unroll
    for (int j = 0; j < 8; ++j) {
      unsigned int lo = (unsigned short)f2bf(bf2f(cr0[j]) * cdv0);
      unsigned int hi = (unsigned short)f2bf(bf2f(cr1[j]) * cdv1);
      x32[(p0w + j) * 68 + s2] = lo | (hi << 16);
    }
  }
  __syncthreads();

  for (int hh = 0; hh < 16; ++hh) {
    const int h = g * 16 + hh;
    float ndv0 = 0.f, ndv1 = 0.f; short8 nr0, nr1;
    if (hh < 15) {
      const int h2 = h + 1;
      const float* acg = acum + ((size_t)(b * NH + h2)) * S_LEN + z * 128;
      const float* dts = dtT + ((size_t)(b * NH + h2)) * S_LEN + z * 128;
      const float acL = acg[127];
      ndv0 = dts[2 * s2] * __expf(acL - acg[2 * s2]);
      ndv1 = dts[2 * s2 + 1] * __expf(acL - acg[2 * s2 + 1]);
      const short* rsrc = hrow + (size_t)(2 * s2) * CONVD + (size_t)h2 * PD + p0w;
      nr0 = *(const short8*)(rsrc);
      nr1 = *(const short8*)(rsrc + CONVD);
    }
    const short* sx = sxdt2[hh & 1];
    f32x4 st[4] = {};
#pragma unroll
    for (int kk = 0; kk < 4; ++kk) {
      short8 a = *(const short8*)(sx + (pband + fr) * 136 + kk * 32 + fk8);
#pragma unroll
      for (int ni = 0; ni < 4; ++ni) {
        short8 bb = *(const short8*)(sBT + (nhalf + ni * 16 + fr) * 136 + kk * 32 + fk8);
        st[ni] = mfma16(a, bb, st[ni]);
      }
    }
    float* stp = states + (((size_t)(b * NC + z)) * NH + h) * (size_t)(NS * PD);
#pragma unroll
    for (int ni = 0; ni < 4; ++ni)
#pragma unroll
      for (int j = 0; j < 4; ++j)
        stp[(pband + er + j) * NS + nhalf + ni * 16 + ec] = st[ni][j];
    if (hh < 15) {
      unsigned int* x32 = (unsigned int*)sxdt2[(hh + 1) & 1];
#pragma unroll
      for (int j = 0; j < 8; ++j) {
        unsigned int lo = (unsigned short)f2bf(bf2f(nr0[j]) * ndv0);
        unsigned int hi = (unsigned short)f2bf(bf2f(nr1[j]) * ndv1);
        x32[(p0w + j) * 68 + s2] = lo | (hi << 16);
      }
    }
    __syncthreads();
  }
}

// ---------------------------------------------------------------- inter-chunk scan
__global__ __launch_bounds__(256) void scan_k(float* __restrict__ states,
                                              const float* __restrict__ acum) {
  const int h = blockIdx.x, b = blockIdx.y;
  const int tid = threadIdx.x;
  float* stp = states + ((size_t)(b * NC * NH) + h) * (size_t)(NS * PD);
  const size_t cst = (size_t)NH * NS * PD;
  const float* ac = acum + ((size_t)(b * NH + h)) * S_LEN;
  float E[32];
#pragma unroll
  for (int i = 0; i < 32; ++i) E[i] = 0.f;
  const int n = tid & 127, pg = tid >> 7;
  for (int zz = 0; zz < NC; ++zz) {
    float* sz = stp + (size_t)zz * cst;
    short* pvb = (short*)sz;
    float tmp[32];
#pragma unroll
    for (int i = 0; i < 32; ++i) tmp[i] = sz[i * 256 + tid];
    __syncthreads();
    float dec = __expf(ac[zz * 128 + 127]);
#pragma unroll
    for (int i = 0; i < 32; ++i) {
      int p = i * 2 + pg;
      pvb[p * 128 + n] = f2bf(E[i]);   // prev entering chunk zz, bf16 [p][n]
      E[i] = dec * E[i] + tmp[i];
    }
    __syncthreads();
  }
}

// ---------------------------------------------------------------- fused Y + gate + group-RMS-norm per (b,z,g)
#define RDSW(BUF, ROWBASE, KK) \
  (*(const short8*)((BUF) + ((ROWBASE) + fr) * 128 + ((((KK) * 4 + slot4) ^ sw7) << 3)))

#define WRX(DST, D0, D1, R0, R1) do { \
  unsigned int* _x = (unsigned int*)(DST); \
  _Pragma("unroll") \
  for (int _j = 0; _j < 8; ++_j) { \
    unsigned int _lo = (unsigned short)f2bf(bf2f(R0[_j]) * (D0)); \
    unsigned int _hi = (unsigned short)f2bf(bf2f(R1[_j]) * (D1)); \
    _x[(p0w + _j) * 64 + ((((s2 >> 2) ^ _j) << 2) | (s2 & 3))] = _lo | (_hi << 16); \
  } \
} while (0)

#define WRP(DST, P0, P1) do { \
  int _p = tid >> 3; int _s0 = (tid & 7) * 2; int _m = _p & 7; \
  *(short8*)((DST) + _p * 128 + ((_s0 ^ _m) << 3)) = P0; \
  *(short8*)((DST) + _p * 128 + (((_s0 + 1) ^ _m) << 3)) = P1; \
} while (0)

#define LOADH_Y(H, DT0, DT1, ACS, ACL, R0, R1, P0, P1) do { \
  const float* _ac = acum + ((size_t)(b * NH + (H))) * S_LEN + z * 128; \
  const float* _dts = dtT + ((size_t)(b * NH + (H))) * S_LEN + z * 128; \
  DT0 = _dts[2 * s2]; DT1 = _dts[2 * s2 + 1]; \
  _Pragma("unroll") \
  for (int _si = 0; _si < 8; ++_si) ACS[_si] = _ac[_si * 16 + ec]; \
  _Pragma("unroll") \
  for (int _j = 0; _j < 4; ++_j) ACL[_j] = _ac[lrow + er + _j]; \
  const short* _rs = hrow + (size_t)(2 * s2) * CONVD + (size_t)(H) * PD + p0w; \
  R0 = *(const short8*)(_rs); R1 = *(const short8*)(_rs + CONVD); \
  const short* _pv = (const short*)(states + (((size_t)(b * NC + z)) * NH + (H)) * (size_t)(NS * PD)); \
  P0 = *(const short8*)(_pv + tid * 16); P1 = *(const short8*)(_pv + tid * 16 + 8); \
} while (0)

__global__ __launch_bounds__(512) void yfull_k(const short* __restrict__ hbc,
                                               const short* __restrict__ projb,
                                               const float* __restrict__ dtT,
                                               const float* __restrict__ acum,
                                               const float* __restrict__ states,
                                               const float* __restrict__ Dv,
                                               const float* __restrict__ norm_w,
                                               short* __restrict__ normed) {
  __shared__ short lds[66560];  // sC 16384 | sB 16384 (->sx1+sp1) | sx0 8192 | sp0 8192 | sP 8*2176
  __shared__ float sScale[128];
  __shared__ float sNW[1024];
  short* sC = lds;
  short* sB = lds + 16384;
  short* sx0 = lds + 32768;
  short* sp0 = lds + 40960;
  const int tid = threadIdx.x, wid = tid >> 6, lane = tid & 63;
  short* sPw = lds + 49152 + wid * 2176;
  const int g = blockIdx.x, z = blockIdx.y, b = blockIdx.z;
  const size_t srow0 = (size_t)(b * S_LEN + z * 128);
  const short* hrow = hbc + srow0 * CONVD;

  {  // gl_lds staging with pre-swizzled source (slot_g = slot ^ (row&7))
    const int slot_g = (lane & 15) ^ (((wid & 1) << 2) | (lane >> 4));
    const int n0_ = slot_g * 8;
#pragma unroll
    for (int it = 0; it < 4; ++it) {
      int s = it * 32 + wid * 4 + (lane >> 4);
      gl_lds16(hrow + (size_t)s * CONVD + INTER + GN + g * NS + n0_, sC + (it * 32 + wid * 4) * 128);
      gl_lds16(hrow + (size_t)s * CONVD + INTER + g * NS + n0_, sB + (it * 32 + wid * 4) * 128);
    }
  }
  for (int i = tid; i < 1024; i += 512) sNW[i] = norm_w[g * 1024 + i];
  __syncthreads();  // sC/sB staged

  const int fr = lane & 15, fk8 = (lane >> 4) * 8;
  const int slot4 = lane >> 4, sw7 = lane & 7;
  const int er = (lane >> 4) * 4, ec = lane & 15;
  const int lrow = wid * 16;
  const int s2 = tid & 63, p0w = (tid >> 6) * 8;

  // prefetch head 0 (latency hides under scores)
  float cdt0, cdt1, cacS[8], cacl[4];
  short8 cr0, cr1, cp0, cp1;
  LOADH_Y(g * 16, cdt0, cdt1, cacS, cacl, cr0, cr1, cp0, cp1);

  // scores C·B^T once (fp32 regs)
  f32x4 sc[8] = {};
#pragma unroll
  for (int kk = 0; kk < 4; ++kk) {
    short8 a = RDSW(sC, lrow, kk);
#pragma unroll
    for (int si = 0; si < 8; ++si) {
      short8 bv = RDSW(sB, si * 16, kk);
      sc[si] = mfma16(a, bv, sc[si]);
    }
  }
  WRX(sx0, cdt0, cdt1, cr0, cr1);
  WRP(sp0, cp0, cp1);
  __syncthreads();  // all waves past scores (sB free) + buf0 visible

  float rssq[4] = {0.f, 0.f, 0.f, 0.f};

  for (int hh = 0; hh < 16; ++hh) {
    const int h = g * 16 + hh;
    float ndt0 = 0.f, ndt1 = 0.f, nacS[8], nacl[4];
    short8 nr0, nr1, np0, np1;
    if (hh < 15) LOADH_Y(h + 1, ndt0, ndt1, nacS, nacl, nr0, nr1, np0, np1);

    short* sx = (hh & 1) ? sB : sx0;
    short* sp = (hh & 1) ? (sB + 8192) : sp0;

    // mask raw scores -> P (bf16) in this wave's private band
#pragma unroll
    for (int j = 0; j < 4; ++j) {
      int lloc = er + j;
      float acl = cacl[j];
#pragma unroll
      for (int si = 0; si < 8; ++si) {
        int sI = si * 16 + ec;
        float v = (sI <= lrow + lloc) ? sc[si][j] * __expf(acl - cacS[si]) : 0.f;
        sPw[lloc * 136 + sI] = f2bf(v);
      }
    }
    f32x4 yd[4] = {}, yo[4] = {};
#pragma unroll
    for (int kk = 0; kk < 4; ++kk) {
      short8 ap = *(const short8*)(sPw + fr * 136 + kk * 32 + fk8);
      short8 acf = RDSW(sC, lrow, kk);
#pragma unroll
      for (int ni = 0; ni < 4; ++ni) {
        short8 bv = RDSW(sx, ni * 16, kk);
        yd[ni] = mfma16(ap, bv, yd[ni]);
        short8 bp = RDSW(sp, ni * 16, kk);
        yo[ni] = mfma16(acf, bp, yo[ni]);
      }
    }
    const float Dh = Dv[h];
#pragma unroll
    for (int j = 0; j < 4; ++j) {
      int l = lrow + er + j;
      float e_ac = __expf(cacl[j]);
#pragma unroll
      for (int ni = 0; ni < 4; ++ni) {
        int p = ni * 16 + ec;
        float hs = bf2f(hrow[(size_t)l * CONVD + (size_t)h * PD + p]);
        float y = yd[ni][j] + yo[ni][j] * e_ac + hs * Dh;
        float gate = bf2f(projb[(srow0 + l) * (size_t)PROJP + (size_t)h * PD + p]);
        float gg = y * gate * sigmoidf_(gate);
        normed[(srow0 + l) * (size_t)INTER + (size_t)h * PD + p] = f2bf(gg);
        rssq[j] += gg * gg;
      }
    }
    if (hh < 15) {
      short* nx = (hh & 1) ? sx0 : sB;
      short* npv = (hh & 1) ? sp0 : (sB + 8192);
      WRX(nx, ndt0, ndt1, nr0, nr1);
      WRP(npv, np0, np1);
      cdt0 = ndt0; cdt1 = ndt1; cr0 = nr0; cr1 = nr1; cp0 = np0; cp1 = np1;
#pragma unroll
      for (int si = 0; si < 8; ++si) cacS[si] = nacS[si];
#pragma unroll
      for (int j = 0; j < 4; ++j) cacl[j] = nacl[j];
    }
    __syncthreads();
  }

#pragma unroll
  for (int j = 0; j < 4; ++j) {
#pragma unroll
    for (int m = 1; m <= 8; m <<= 1) rssq[j] += __shfl_xor(rssq[j], m, 64);
  }
  if (ec == 0) {
#pragma unroll
    for (int j = 0; j < 4; ++j) sScale[lrow + er + j] = rsqrtf(rssq[j] * (1.f / 1024.f) + 1e-5f);
  }
  __syncthreads();  // drains vmcnt -> all gg writes visible

  // in-place rescale of the block's 128x1024 bf16 slab
  for (int e = tid * 8; e < 128 * 1024; e += 4096) {
    int row = e >> 10, ch = e & 1023;
    short* gp = normed + (srow0 + row) * (size_t)INTER + g * 1024 + ch;
    short8 gv = *(const short8*)(gp);
    float scl = sScale[row];
    short8 o;
#pragma unroll
    for (int q = 0; q < 8; ++q) o[q] = f2bf(bf2f(gv[q]) * scl * sNW[ch + q]);
    *(short8*)(gp) = o;
  }
}

// ----------------------------------------------------------------
extern "C" void kernel_launch(void* const* d_in, const int* in_sizes, int n_in,
                              void* d_out, int out_size, void* d_ws, size_t ws_size,
                              hipStream_t stream) {
  const float* x     = (const float*)d_in[0];
  const float* w1    = (const float*)d_in[1];
  const float* convw = (const float*)d_in[2];
  const float* convb = (const float*)d_in[3];
  const float* dtb   = (const float*)d_in[4];
  const float* alog  = (const float*)d_in[5];
  const float* Dv    = (const float*)d_in[6];
  const float* nw    = (const float*)d_in[7];
  const float* w2    = (const float*)d_in[8];
  float* out = (float*)d_out;

  char* ws = (char*)d_ws;
  size_t off = 0;
  float* dtT = (float*)(ws + off);  off += (size_t)BB * NH * S_LEN * 4;
  float* acum = (float*)(ws + off); off += (size_t)BB * NH * S_LEN * 4;
  short* xb = (short*)(ws + off);   off += (size_t)BS * HID_DIM * 2;
  char* w1region = ws + off;        off += (size_t)PROJP * HID_DIM * 2;
  short* w1b = (short*)w1region;
  short* normed = (short*)w1region;                              // reuse after gemm1
  short* w2b = (short*)(w1region + (size_t)BS * INTER * 2);      // reuse after gemm1
  short* projb = (short*)(ws + off); off += (size_t)BS * PROJP * 2;
  short* hbc = (short*)(ws + off);   off += (size_t)BS * CONVD * 2;
  float* states = (float*)(ws + off); off += (size_t)BB * NC * NH * NS * PD * 4;

  const size_t nx = (size_t)BS * HID_DIM;
  const size_t nw1 = (size_t)PROJ * HID_DIM;
  const size_t nw2 = (size_t)HID_DIM * INTER;

  cvt_f32_bf16_k<<<dim3(nx / 2048), 256, 0, stream>>>(x, xb, nx);
  cvt_f32_bf16_k<<<dim3(nw1 / 2048), 256, 0, stream>>>(w1, w1b, nw1);

  // gemm1: [4096 x 18560(pad 18688)] = xb[4096x4096] * w1b^T ; 16 x 73 tiles
  gemm256_k<1><<<dim3(16 * 73), 512, 0, stream>>>(xb, w1b, projb, PROJP, HID_DIM, 73);

  // w1b dead now; stage w2 into its region
  cvt_f32_bf16_k<<<dim3(nw2 / 2048), 256, 0, stream>>>(w2, w2b, nw2);

  conv_silu_k<<<dim3(CONVD / 256, S_LEN / 256, BB), 256, 0, stream>>>(projb, convw, convb, hbc);
  acum_k<<<dim3(NC, NH, BB), 128, 0, stream>>>(projb, dtb, alog, dtT, acum);

  states_k<<<dim3(NG, NC, BB), 512, 0, stream>>>(hbc, dtT, acum, states);
  scan_k<<<dim3(NH, BB), 256, 0, stream>>>(states, acum);
  yfull_k<<<dim3(NG, NC, BB), 512, 0, stream>>>(hbc, projb, dtT, acum, states, Dv, nw, normed);

  // gemm2: [4096 x 4096] = normed[4096x8192] * w2b^T ; 16 x 16 tiles
  gemm256_k<0><<<dim3(16 * 16), 512, 0, stream>>>(normed, w2b, out, HID_DIM, INTER, 16);
}